// Round 6
// baseline (126.922 us; speedup 1.0000x reference)
//
#include <hip/hip_runtime.h>
#include <hip/hip_bf16.h>

// FractalAttention on MI355X.
// Math: per level k, out = reshape-scatter( (x viewed [8192,1024]) @ Mcat_k + b ),
// where Mcat_k[j*128+d, h*128+e] = sum_d' W[k,h,d,d'] * w_mix[j*128+d', e].
// Precision: Mcat computed via 3-term bf16 hi/lo MFMA (near-fp32), stored fp16.
// Levels: single-plane fp16 MFMA, BM=128/BN=256 tile, 512 thr (8 waves 2x4),
// 3-deep LDS pipeline, counted vmcnt(6), 1 barrier/K-tile, 4 phases/K-tile
// with setprio(1) MFMA clusters (T3/T4/T5) + XOR bank swizzle (T2).

typedef __attribute__((ext_vector_type(8))) __bf16 bf16x8;
typedef __attribute__((ext_vector_type(8))) _Float16 half8;
typedef __attribute__((ext_vector_type(4))) float f32x4;
typedef __attribute__((ext_vector_type(4))) unsigned short us4;
typedef __attribute__((ext_vector_type(8))) unsigned short us8;

#define DEVI static __device__ __forceinline__

DEVI unsigned short f2bf(float f) {
  unsigned u = __builtin_bit_cast(unsigned, f);
  unsigned r = (u + 0x7fffu + ((u >> 16) & 1u)) >> 16;
  return (unsigned short)r;
}
DEVI float bf2f(unsigned short s) {
  return __builtin_bit_cast(float, (unsigned)s << 16);
}
DEVI unsigned short f2h(float f) {
  return __builtin_bit_cast(unsigned short, (_Float16)f);
}

DEVI void gload_lds16(const void* g, void* l) {
  __builtin_amdgcn_global_load_lds(
      (const __attribute__((address_space(1))) void*)g,
      (__attribute__((address_space(3))) void*)l,
      16, 0, 0);
}

// ---------------------------------------------------------------------------
// fp32 -> bf16 hi/lo planes (used for W; feeds the high-precision precompute)
// ---------------------------------------------------------------------------
__global__ __launch_bounds__(256) void split_kernel(
    const float* __restrict__ x, unsigned short* __restrict__ hi,
    unsigned short* __restrict__ lo, int n4)
{
  const int stride = gridDim.x * 256;
  for (int i = blockIdx.x * 256 + threadIdx.x; i < n4; i += stride) {
    const float4 v = ((const float4*)x)[i];
    float vv[4] = {v.x, v.y, v.z, v.w};
    us4 hv, lv;
#pragma unroll
    for (int t = 0; t < 4; ++t) {
      const unsigned short hb = f2bf(vv[t]);
      hv[t] = hb;
      lv[t] = f2bf(vv[t] - bf2f(hb));
    }
    ((us4*)hi)[i] = hv;
    ((us4*)lo)[i] = lv;
  }
}

// ---------------------------------------------------------------------------
// fp32 -> fp16 single plane (x input)
// ---------------------------------------------------------------------------
__global__ __launch_bounds__(256) void split_f16(
    const float* __restrict__ x, unsigned short* __restrict__ o, int n4)
{
  const int stride = gridDim.x * 256;
  for (int i = blockIdx.x * 256 + threadIdx.x; i < n4; i += stride) {
    const float4 v = ((const float4*)x)[i];
    us4 hv;
    hv[0] = f2h(v.x);
    hv[1] = f2h(v.y);
    hv[2] = f2h(v.z);
    hv[3] = f2h(v.w);
    ((us4*)o)[i] = hv;
  }
}

// ---------------------------------------------------------------------------
// wmix [1024(j*128+d2)][128(e)] fp32 -> wmixT [128(e)][1024(j*128+d2)]
// bf16 hi/lo planes. grid = 8 (j), block = 256. LDS transpose, padded.
// ---------------------------------------------------------------------------
__global__ __launch_bounds__(256) void wmixT_split(
    const float* __restrict__ wmix, unsigned short* __restrict__ Th,
    unsigned short* __restrict__ Tl)
{
  __shared__ float sT[128][129];
  const int j = blockIdx.x;
  const int tid = threadIdx.x;
  const float* src = wmix + (size_t)j * 16384;
  for (int i = tid; i < 16384 / 4; i += 256) {
    const int d2 = i >> 5;
    const int e4 = (i & 31) * 4;
    const float4 v = *(const float4*)(src + d2 * 128 + e4);
    sT[e4 + 0][d2] = v.x;
    sT[e4 + 1][d2] = v.y;
    sT[e4 + 2][d2] = v.z;
    sT[e4 + 3][d2] = v.w;
  }
  __syncthreads();
  const int e = tid >> 1;
  const int d2h = (tid & 1) * 64;
  const size_t base = (size_t)e * 1024 + j * 128 + d2h;
#pragma unroll
  for (int r = 0; r < 8; ++r) {
    us8 hv, lv;
#pragma unroll
    for (int t = 0; t < 8; ++t) {
      const float m = sT[e][d2h + r * 8 + t];
      const unsigned short hb = f2bf(m);
      hv[t] = hb;
      lv[t] = f2bf(m - bf2f(hb));
    }
    *(us8*)(Th + base + r * 8) = hv;
    *(us8*)(Tl + base + r * 8) = lv;
  }
}

// ---------------------------------------------------------------------------
// MFMA precompute: for (lvl,h,j): MT16[lvlh*131072 + e*1024 + j*128 + d]
//   = sum_d2 wmixT[e][j*128+d2] * W[lvlh][d][d2]   (3-term hi/lo, fp16 out)
// grid = (8 j, 32 lvlh), block = 256 (4 waves, 2x2), K=128 in 2 steps of 64.
// ---------------------------------------------------------------------------
__global__ __launch_bounds__(256, 2) void precompute_MT_mfma(
    const unsigned short* __restrict__ Ah, const unsigned short* __restrict__ Al,
    const unsigned short* __restrict__ Bh, const unsigned short* __restrict__ Bl,
    unsigned short* __restrict__ MT16)
{
  __shared__ unsigned short sAh[128 * 64];
  __shared__ unsigned short sAl[128 * 64];
  __shared__ unsigned short sBh[128 * 64];
  __shared__ unsigned short sBl[128 * 64];

  const int tid = threadIdx.x;
  const int j = blockIdx.x;
  const int lvlh = blockIdx.y;

  const int w = tid >> 6, lane = tid & 63;
  const int srow = w * 8 + (lane >> 3);
  const int scol = (lane & 7) * 8;
  // A rows (e): wmixT row stride 1024
  const size_t aoff = (size_t)srow * 1024 + j * 128 + scol;
  // B rows (d): W row stride 128
  const size_t boff = (size_t)lvlh * 16384 + (size_t)srow * 128 + scol;
  const int ldst = w * 512;

  f32x4 acc[4][4] = {};
  const int wm = w >> 1, wn = w & 1;

  for (int kb = 0; kb < 2; ++kb) {
    const int kc = kb * 64;
#pragma unroll
    for (int i = 0; i < 4; ++i) {
      const int lo_ = ldst + i * 2048;
      gload_lds16(Ah + aoff + (size_t)i * 32 * 1024 + kc, sAh + lo_);
      gload_lds16(Al + aoff + (size_t)i * 32 * 1024 + kc, sAl + lo_);
      gload_lds16(Bh + boff + (size_t)i * 32 * 128 + kc, sBh + lo_);
      gload_lds16(Bl + boff + (size_t)i * 32 * 128 + kc, sBl + lo_);
    }
    __syncthreads();
#pragma unroll
    for (int kk = 0; kk < 2; ++kk) {
      bf16x8 fah[4], fal[4], fbh[4], fbl[4];
      const int ko = kk * 32 + ((lane >> 4) << 3);
#pragma unroll
      for (int m = 0; m < 4; ++m) {
        const int row = wm * 64 + m * 16 + (lane & 15);
        fah[m] = *(const bf16x8*)(sAh + row * 64 + ko);
        fal[m] = *(const bf16x8*)(sAl + row * 64 + ko);
      }
#pragma unroll
      for (int n = 0; n < 4; ++n) {
        const int col = wn * 64 + n * 16 + (lane & 15);
        fbh[n] = *(const bf16x8*)(sBh + col * 64 + ko);
        fbl[n] = *(const bf16x8*)(sBl + col * 64 + ko);
      }
#pragma unroll
      for (int m = 0; m < 4; ++m) {
#pragma unroll
        for (int n = 0; n < 4; ++n) {
          acc[m][n] = __builtin_amdgcn_mfma_f32_16x16x32_bf16(
              fah[m], fbh[n], acc[m][n], 0, 0, 0);
          acc[m][n] = __builtin_amdgcn_mfma_f32_16x16x32_bf16(
              fah[m], fbl[n], acc[m][n], 0, 0, 0);
          acc[m][n] = __builtin_amdgcn_mfma_f32_16x16x32_bf16(
              fal[m], fbh[n], acc[m][n], 0, 0, 0);
        }
      }
    }
    __syncthreads();
  }

  // C[e][d] -> MT16[lvlh*131072 + e*1024 + j*128 + d], fp16
  const size_t mtbase = (size_t)lvlh * 131072 + (size_t)j * 128;
#pragma unroll
  for (int m = 0; m < 4; ++m) {
#pragma unroll
    for (int n = 0; n < 4; ++n) {
      const int d = wn * 64 + n * 16 + (lane & 15);
#pragma unroll
      for (int i = 0; i < 4; ++i) {
        const int e = wm * 64 + m * 16 + ((lane >> 4) << 2) + i;
        MT16[mtbase + (size_t)e * 1024 + d] = f2h(acc[m][n][i]);
      }
    }
  }
}

// ---------------------------------------------------------------------------
// Level GEMM (fp16, deep pipeline): C[8192,1024] = A @ Mcat + bias, with the
// per-(128-col block h) output row remap.
// BM=128, BN=256, BK=64; 512 threads = 8 waves (2M x 4N), 64x64 per wave.
// 3 LDS buffers (144 KB) -> prefetch leads compute by 2 K-tiles.
// Per K-tile: vmcnt(6); barrier; 4 phases {stage-issue, ds_read, prio MFMA}.
// grid = (64 rowtiles, 4 coltiles) = 256 blocks = 1/CU.
// ---------------------------------------------------------------------------
template <int OUT_MODE>
__global__ __launch_bounds__(512, 2) void level_gemm_f16(
    const unsigned short* __restrict__ A, const unsigned short* __restrict__ B,
    const float* __restrict__ bias, unsigned short* __restrict__ O16,
    float* __restrict__ Ofp, int lshift)
{
  __shared__ unsigned short sA[3][128 * 64];
  __shared__ unsigned short sB[3][256 * 64];

  const int tid = threadIdx.x;
  const int g0 = blockIdx.x * 128;   // A row-tile start
  const int cb = blockIdx.y;         // 256-col tile

  const int w = tid >> 6, lane = tid & 63;
  const int wm = w >> 2, wn = w & 3;

  // staging: round covers 64 rows x 64 cols (8 KB); 1 instr/thread/round.
  // A: rounds 0-1; B: rounds 0-3. LDS dest lane-linear; source col swizzled
  // by the (slot ^ row&7) involution so swizzled reads see linear data (T2).
  const int strow = tid >> 3;                         // 0..63
  const int xcol = ((tid & 7) ^ (strow & 7)) * 8;
  const size_t abase = (size_t)(g0 + strow) * 1024 + xcol;
  const size_t bbase = (size_t)(cb * 256 + strow) * 1024 + xcol;
  const int ldsw = (w * 8) * 64;  // wave-uniform elem base within a round

#define STG_A(buf, t, r)                                                    \
  gload_lds16(A + abase + (size_t)(r) * 65536 + (t) * 64,                   \
              (buf) + (r) * 4096 + ldsw)
#define STG_B(buf, t, r)                                                    \
  gload_lds16(B + bbase + (size_t)(r) * 65536 + (t) * 64,                   \
              (buf) + (r) * 4096 + ldsw)

  f32x4 acc[4][4] = {};

  unsigned short *a0 = sA[0], *a1 = sA[1], *a2 = sA[2];
  unsigned short *b0 = sB[0], *b1 = sB[1], *b2 = sB[2];

  // prologue: stage tiles 0 and 1 (6 rounds each)
  STG_A(a0, 0, 0); STG_A(a0, 0, 1);
  STG_B(b0, 0, 0); STG_B(b0, 0, 1); STG_B(b0, 0, 2); STG_B(b0, 0, 3);
  STG_A(a1, 1, 0); STG_A(a1, 1, 1);
  STG_B(b1, 1, 0); STG_B(b1, 1, 1); STG_B(b1, 1, 2); STG_B(b1, 1, 3);

  // fragment read addressing (row&7 == lane&7 for all frag rows)
  const int l15 = lane & 15;
  const int koX = ((lane >> 4) << 3) ^ ((lane & 7) << 3);  // kk=0 slot
  const int ko0 = koX;
  const int ko1 = (32 + ((lane >> 4) << 3)) ^ ((lane & 7) << 3);

#define LDA(dst, buf, m, ko)                                                \
  dst = *(const half8*)((buf) + (wm * 64 + (m)*16 + l15) * 64 + (ko))
#define LDB(dst, buf, n, ko)                                                \
  dst = *(const half8*)((buf) + (wn * 64 + (n)*16 + l15) * 64 + (ko))

#define SBAR()                                                              \
  __builtin_amdgcn_sched_barrier(0);                                        \
  __builtin_amdgcn_s_barrier();                                             \
  __builtin_amdgcn_sched_barrier(0)

#pragma unroll 1
  for (int t = 0; t < 16; ++t) {
    if (t < 15) {
      asm volatile("s_waitcnt vmcnt(6)" ::: "memory");
    } else {
      asm volatile("s_waitcnt vmcnt(0)" ::: "memory");
    }
    SBAR();
    const bool pf = (t + 2 < 16);
    half8 fb0, fb1, fb2, fb3, faA, faB;

    // ---- phase 0: kk0, m=0..1
    if (pf) { STG_A(a2, t + 2, 0); STG_A(a2, t + 2, 1); }
    LDB(fb0, b0, 0, ko0); LDB(fb1, b0, 1, ko0);
    LDB(fb2, b0, 2, ko0); LDB(fb3, b0, 3, ko0);
    LDA(faA, a0, 0, ko0); LDA(faB, a0, 1, ko0);
    __builtin_amdgcn_s_setprio(1);
    acc[0][0] = __builtin_amdgcn_mfma_f32_16x16x32_f16(faA, fb0, acc[0][0], 0, 0, 0);
    acc[0][1] = __builtin_amdgcn_mfma_f32_16x16x32_f16(faA, fb1, acc[0][1], 0, 0, 0);
    acc[0][2] = __builtin_amdgcn_mfma_f32_16x16x32_f16(faA, fb2, acc[0][2], 0, 0, 0);
    acc[0][3] = __builtin_amdgcn_mfma_f32_16x16x32_f16(faA, fb3, acc[0][3], 0, 0, 0);
    acc[1][0] = __builtin_amdgcn_mfma_f32_16x16x32_f16(faB, fb0, acc[1][0], 0, 0, 0);
    acc[1][1] = __builtin_amdgcn_mfma_f32_16x16x32_f16(faB, fb1, acc[1][1], 0, 0, 0);
    acc[1][2] = __builtin_amdgcn_mfma_f32_16x16x32_f16(faB, fb2, acc[1][2], 0, 0, 0);
    acc[1][3] = __builtin_amdgcn_mfma_f32_16x16x32_f16(faB, fb3, acc[1][3], 0, 0, 0);
    __builtin_amdgcn_s_setprio(0);
    __builtin_amdgcn_sched_barrier(0);

    // ---- phase 1: kk0, m=2..3
    if (pf) STG_B(b2, t + 2, 0);
    LDA(faA, a0, 2, ko0); LDA(faB, a0, 3, ko0);
    __builtin_amdgcn_s_setprio(1);
    acc[2][0] = __builtin_amdgcn_mfma_f32_16x16x32_f16(faA, fb0, acc[2][0], 0, 0, 0);
    acc[2][1] = __builtin_amdgcn_mfma_f32_16x16x32_f16(faA, fb1, acc[2][1], 0, 0, 0);
    acc[2][2] = __builtin_amdgcn_mfma_f32_16x16x32_f16(faA, fb2, acc[2][2], 0, 0, 0);
    acc[2][3] = __builtin_amdgcn_mfma_f32_16x16x32_f16(faA, fb3, acc[2][3], 0, 0, 0);
    acc[3][0] = __builtin_amdgcn_mfma_f32_16x16x32_f16(faB, fb0, acc[3][0], 0, 0, 0);
    acc[3][1] = __builtin_amdgcn_mfma_f32_16x16x32_f16(faB, fb1, acc[3][1], 0, 0, 0);
    acc[3][2] = __builtin_amdgcn_mfma_f32_16x16x32_f16(faB, fb2, acc[3][2], 0, 0, 0);
    acc[3][3] = __builtin_amdgcn_mfma_f32_16x16x32_f16(faB, fb3, acc[3][3], 0, 0, 0);
    __builtin_amdgcn_s_setprio(0);
    __builtin_amdgcn_sched_barrier(0);

    // ---- phase 2: kk1, m=0..1
    if (pf) { STG_B(b2, t + 2, 1); STG_B(b2, t + 2, 2); }
    LDB(fb0, b0, 0, ko1); LDB(fb1, b0, 1, ko1);
    LDB(fb2, b0, 2, ko1); LDB(fb3, b0, 3, ko1);
    LDA(faA, a0, 0, ko1); LDA(faB, a0, 1, ko1);
    __builtin_amdgcn_s_setprio(1);
    acc[0][0] = __builtin_amdgcn_mfma_f32_16x16x32_f16(faA, fb0, acc[0][0], 0, 0, 0);
    acc[0][1] = __builtin_amdgcn_mfma_f32_16x16x32_f16(faA, fb1, acc[0][1], 0, 0, 0);
    acc[0][2] = __builtin_amdgcn_mfma_f32_16x16x32_f16(faA, fb2, acc[0][2], 0, 0, 0);
    acc[0][3] = __builtin_amdgcn_mfma_f32_16x16x32_f16(faA, fb3, acc[0][3], 0, 0, 0);
    acc[1][0] = __builtin_amdgcn_mfma_f32_16x16x32_f16(faB, fb0, acc[1][0], 0, 0, 0);
    acc[1][1] = __builtin_amdgcn_mfma_f32_16x16x32_f16(faB, fb1, acc[1][1], 0, 0, 0);
    acc[1][2] = __builtin_amdgcn_mfma_f32_16x16x32_f16(faB, fb2, acc[1][2], 0, 0, 0);
    acc[1][3] = __builtin_amdgcn_mfma_f32_16x16x32_f16(faB, fb3, acc[1][3], 0, 0, 0);
    __builtin_amdgcn_s_setprio(0);
    __builtin_amdgcn_sched_barrier(0);

    // ---- phase 3: kk1, m=2..3
    if (pf) STG_B(b2, t + 2, 3);
    LDA(faA, a0, 2, ko1); LDA(faB, a0, 3, ko1);
    __builtin_amdgcn_s_setprio(1);
    acc[2][0] = __builtin_amdgcn_mfma_f32_16x16x32_f16(faA, fb0, acc[2][0], 0, 0, 0);
    acc[2][1] = __builtin_amdgcn_mfma_f32_16x16x32_f16(faA, fb1, acc[2][1], 0, 0, 0);
    acc[2][2] = __builtin_amdgcn_mfma_f32_16x16x32_f16(faA, fb2, acc[2][2], 0, 0, 0);
    acc[2][3] = __builtin_amdgcn_mfma_f32_16x16x32_f16(faA, fb3, acc[2][3], 0, 0, 0);
    acc[3][0] = __builtin_amdgcn_mfma_f32_16x16x32_f16(faB, fb0, acc[3][0], 0, 0, 0);
    acc[3][1] = __builtin_amdgcn_mfma_f32_16x16x32_f16(faB, fb1, acc[3][1], 0, 0, 0);
    acc[3][2] = __builtin_amdgcn_mfma_f32_16x16x32_f16(faB, fb2, acc[3][2], 0, 0, 0);
    acc[3][3] = __builtin_amdgcn_mfma_f32_16x16x32_f16(faB, fb3, acc[3][3], 0, 0, 0);
    __builtin_amdgcn_s_setprio(0);
    __builtin_amdgcn_sched_barrier(0);

    // rotate buffers
    unsigned short* ta = a0; a0 = a1; a1 = a2; a2 = ta;
    unsigned short* tb = b0; b0 = b1; b1 = b2; b2 = tb;
  }
#undef STG_A
#undef STG_B
#undef LDA
#undef LDB

  // Epilogue: out global row = b*8192 + n*L + h*(L/8) + r ; contiguous block.
  const int h = cb * 2 + (wn >> 1);        // per-wave 128-col block
  const int bss = lshift - 3;              // log2(L/8)
  const int q = g0 & 1023;
  const int n_idx = q >> bss;
  const int r0 = q & ((1 << bss) - 1);
  const long srow0 = (long)(g0 >> 10) * 8192 + ((long)n_idx << lshift) +
                     ((long)h << bss) + r0;
  const size_t obase = (size_t)srow0 * 128;

#pragma unroll
  for (int m = 0; m < 4; ++m) {
#pragma unroll
    for (int n = 0; n < 4; ++n) {
      const int col = (wn & 1) * 64 + n * 16 + l15;   // 0..127 within h-block
      const float bv = bias[col];
#pragma unroll
      for (int i = 0; i < 4; ++i) {
        const int row = wm * 64 + m * 16 + ((lane >> 4) << 2) + i;
        const float v = acc[m][n][i] + bv;
        const size_t p = obase + (size_t)row * 128 + col;
        if (OUT_MODE) {
          Ofp[p] = v;
        } else {
          O16[p] = f2h(v);
        }
      }
    }
  }
}

// ---------------------------------------------------------------------------
extern "C" void kernel_launch(void* const* d_in, const int* in_sizes, int n_in,
                              void* d_out, int out_size, void* d_ws,
                              size_t ws_size, hipStream_t stream) {
  const float* x = (const float*)d_in[0];
  const float* W = (const float*)d_in[1];    // [4,8,128,128]
  const float* wmx = (const float*)d_in[2];  // [1024,128]
  const float* bmx = (const float*)d_in[3];  // [128]
  float* out = (float*)d_out;

  const size_t NELEM = 8ull * 8192 * 128;   // 8388608
  const size_t MTSZ = 4ull * 1024 * 1024;   // 4194304 MT16 elems
  const size_t WSZ = 4ull * 8 * 128 * 128;  // 524288 W elems
  const size_t WTSZ = 128ull * 1024;        // 131072 wmixT elems

  // ws layout (ushort elems): MT16 | Wh | Wl | wTh | wTl | Xa | Xc
  unsigned short* MT16 = (unsigned short*)d_ws;
  unsigned short* Wh = MT16 + MTSZ;
  unsigned short* Wl = Wh + WSZ;
  unsigned short* wTh = Wl + WSZ;
  unsigned short* wTl = wTh + WTSZ;
  unsigned short* Xa = wTl + WTSZ;   // 16 MB
  unsigned short* Xc = Xa + NELEM;   // 16 MB
  // d_out lower half doubles as the level-1 output plane
  unsigned short* Xb = (unsigned short*)d_out;

  split_kernel<<<dim3(512), dim3(256), 0, stream>>>(W, Wh, Wl, (int)(WSZ / 4));
  wmixT_split<<<dim3(8), dim3(256), 0, stream>>>(wmx, wTh, wTl);
  precompute_MT_mfma<<<dim3(8, 32), dim3(256), 0, stream>>>(wTh, wTl, Wh, Wl,
                                                            MT16);
  split_f16<<<dim3(2048), dim3(256), 0, stream>>>(x, Xa, (int)(NELEM / 4));

  dim3 grid(64, 4), blk(512);
  // Level 1 (L=1024): Xa -> Xb (d_out lower half)
  level_gemm_f16<0><<<grid, blk, 0, stream>>>(Xa, MT16 + 0 * 1048576ull, bmx,
                                              Xb, nullptr, 10);
  // Level 2 (L=2048): Xb -> Xc
  level_gemm_f16<0><<<grid, blk, 0, stream>>>(Xb, MT16 + 1 * 1048576ull, bmx,
                                              Xc, nullptr, 11);
  // Level 3 (L=4096): Xc -> Xa
  level_gemm_f16<0><<<grid, blk, 0, stream>>>(Xc, MT16 + 2 * 1048576ull, bmx,
                                              Xa, nullptr, 12);
  // Level 4 (L=8192): Xa -> fp32 out (full d_out overwrite)
  level_gemm_f16<1><<<grid, blk, 0, stream>>>(Xa, MT16 + 3 * 1048576ull, bmx,
                                              nullptr, out, 13);
}